// Round 1
// baseline (158.794 us; speedup 1.0000x reference)
//
#include <hip/hip_runtime.h>
#include <stdint.h>

// Problem constants
#define BB 1024
#define MM 128
#define KK 32
#define NEDGE (BB * MM * KK)   // 4194304

static __device__ __forceinline__ unsigned long long shfl_xor_u64(unsigned long long v, int mask) {
    unsigned int lo = (unsigned int)v;
    unsigned int hi = (unsigned int)(v >> 32);
    lo = (unsigned int)__shfl_xor((int)lo, mask, 64);
    hi = (unsigned int)__shfl_xor((int)hi, mask, 64);
    return ((unsigned long long)hi << 32) | (unsigned long long)lo;
}

// One block (256 threads = 4 waves) per batch. Each wave processes 32 rows.
// Per row: 64 lanes hold 2 candidates each; full 128-element bitonic sort on
// key64 = (f32bits(d2m) << 32) | j  — reproduces jax.lax.top_k's stable
// (value, lower-index-first) ordering exactly.
__global__ __launch_bounds__(256, 4) void knn_edges_kernel(const float* __restrict__ pos,
                                                           float* __restrict__ out) {
    __shared__ float px[MM], py[MM], pz[MM], sqs[MM];
    const int b = blockIdx.x;
    const int tid = threadIdx.x;

    if (tid < MM) {
        const float* p = pos + (size_t)(b * MM + tid) * 3;
        float x = p[0], y = p[1], z = p[2];
        px[tid] = x; py[tid] = y; pz[tid] = z;
        // sq = (x*x + y*y) + z*z  -- same association as jnp.sum over axis -1, no FMA
        sqs[tid] = __fadd_rn(__fadd_rn(__fmul_rn(x, x), __fmul_rn(y, y)), __fmul_rn(z, z));
    }
    __syncthreads();

    const int wave = tid >> 6;
    const int lane = tid & 63;

    for (int i = wave * 32; i < wave * 32 + 32; ++i) {
        const float xi = px[i], yi = py[i], zi = pz[i], sqi = sqs[i];

        unsigned long long k0, k1;
        {
            const int j = lane;
            float dot = __fadd_rn(__fadd_rn(__fmul_rn(xi, px[j]), __fmul_rn(yi, py[j])),
                                  __fmul_rn(zi, pz[j]));
            float d2 = __fsub_rn(__fadd_rn(sqi, sqs[j]), __fmul_rn(2.0f, dot));
            d2 = fmaxf(d2, 0.0f);
            unsigned int bits = (d2 < 25.0f) ? __float_as_uint(d2) : 0x7F800000u;
            k0 = ((unsigned long long)bits << 32) | (unsigned int)j;
        }
        {
            const int j = lane + 64;
            float dot = __fadd_rn(__fadd_rn(__fmul_rn(xi, px[j]), __fmul_rn(yi, py[j])),
                                  __fmul_rn(zi, pz[j]));
            float d2 = __fsub_rn(__fadd_rn(sqi, sqs[j]), __fmul_rn(2.0f, dot));
            d2 = fmaxf(d2, 0.0f);
            unsigned int bits = (d2 < 25.0f) ? __float_as_uint(d2) : 0x7F800000u;
            k1 = ((unsigned long long)bits << 32) | (unsigned int)j;
        }

        // ---- bitonic sort of 128 elements: e0 = lane, e1 = 64 + lane ----
        // passes size = 2..64: both elements in lane space, partner via shfl_xor
#pragma unroll
        for (int size = 2; size <= 64; size <<= 1) {
#pragma unroll
            for (int stride = size >> 1; stride >= 1; stride >>= 1) {
                unsigned long long p0 = shfl_xor_u64(k0, stride);
                unsigned long long p1 = shfl_xor_u64(k1, stride);
                bool lower = (lane & stride) == 0;
                bool up0 = (lane & size) == 0;
                bool up1 = (size == 64) ? false : up0;   // (64+lane) & size
                k0 = (lower == up0) ? (p0 < k0 ? p0 : k0) : (p0 > k0 ? p0 : k0);
                k1 = (lower == up1) ? (p1 < k1 ? p1 : k1) : (p1 > k1 ? p1 : k1);
            }
        }
        // final merge pass, size = 128 (ascending everywhere)
        {
            unsigned long long lo = k0 < k1 ? k0 : k1;
            unsigned long long hi = k0 < k1 ? k1 : k0;
            k0 = lo; k1 = hi;
#pragma unroll
            for (int stride = 32; stride >= 1; stride >>= 1) {
                unsigned long long p0 = shfl_xor_u64(k0, stride);
                unsigned long long p1 = shfl_xor_u64(k1, stride);
                bool lower = (lane & stride) == 0;
                k0 = lower ? (p0 < k0 ? p0 : k0) : (p0 > k0 ? p0 : k0);
                k1 = lower ? (p1 < k1 ? p1 : k1) : (p1 > k1 ? p1 : k1);
            }
        }

        // ranks 0..31 are in lanes 0..31, slot 0
        if (lane < KK) {
            const unsigned long long key = k0;
            const unsigned int bits = (unsigned int)(key >> 32);
            const int j = (int)(key & 0xFFFFFFFFu);
            const bool taken = (bits != 0x7F800000u);
            const int sel = taken ? j : i;

            // vec = p[sel] - p[i] (exact subtract); 0 when sel == i
            float dx = __fsub_rn(px[sel], xi);
            float dy = __fsub_rn(py[sel], yi);
            float dz = __fsub_rn(pz[sel], zi);

            float w = 0.0f;
            if (taken && sel != i) {
                // weight = sqrt((dx*dx + dy*dy) + dz*dz), same order as reference
                w = sqrtf(__fadd_rn(__fadd_rn(__fmul_rn(dx, dx), __fmul_rn(dy, dy)),
                                    __fmul_rn(dz, dz)));
            }

            const int e = (b * MM + i) * KK + lane;
            out[e] = (float)(b * MM + sel);                 // edge_index[0] (src)
            out[NEDGE + e] = (float)(b * MM + i);           // edge_index[1] (dst)
            out[2 * (size_t)NEDGE + e] = w;                 // edge_weight
            float* v = out + 3 * (size_t)NEDGE + (size_t)e * 3;
            v[0] = dx; v[1] = dy; v[2] = dz;                // edge_vec
        }
    }
}

extern "C" void kernel_launch(void* const* d_in, const int* in_sizes, int n_in,
                              void* d_out, int out_size, void* d_ws, size_t ws_size,
                              hipStream_t stream) {
    const float* pos = (const float*)d_in[0];
    float* out = (float*)d_out;
    hipLaunchKernelGGL(knn_edges_kernel, dim3(BB), dim3(256), 0, stream, pos, out);
}

// Round 2
// 52.873 us; speedup vs baseline: 3.0033x; 3.0033x over previous
//
#include <hip/hip_runtime.h>
#include <stdint.h>

// Problem constants
#define BB 1024
#define MM 128
#define KK 32
#define NEDGE (BB * MM * KK)   // 4194304
#define BPB 4                  // blocks per batch
#define ROWS_PER_WAVE (MM / (4 * BPB))  // 8

// keep-min lane masks for the bitonic stages (compile-time)
static constexpr unsigned long long p1mask(int size, int stride) {
    unsigned long long m = 0;
    for (int l = 0; l < 64; ++l) {
        int g = l & 31;
        bool up = (((g & size) == 0) != (l >= 32));   // lower half asc, upper half desc
        bool keep = (((g & stride) == 0) == up);
        if (keep) m |= 1ull << l;
    }
    return m;
}
static constexpr unsigned long long cleanmask(int stride) {
    unsigned long long m = 0;
    for (int l = 0; l < 64; ++l) {
        int g = l & 31;
        if ((g & stride) == 0) m |= 1ull << l;
    }
    return m;
}

// compare-exchange via ds_swizzle (xor within 32-lane groups) + cndmask on a
// constant 64-bit SGPR lane mask: 4 instructions total.
template<int STRIDE, unsigned long long KEEPMIN>
static __device__ __forceinline__ unsigned cexs(unsigned k) {
    unsigned p = (unsigned)__builtin_amdgcn_ds_swizzle((int)k, (STRIDE << 10) | 0x1F);
    unsigned mn = k < p ? k : p;
    unsigned mx = k < p ? p : k;
    unsigned r;
    asm("v_cndmask_b32 %0, %1, %2, %3" : "=v"(r) : "v"(mx), "v"(mn), "s"(KEEPMIN));
    return r;
}

static __device__ __forceinline__ unsigned sx32(unsigned v) {
    return (unsigned)__shfl_xor((int)v, 32, 64);
}

// grid = BB*BPB blocks of 256 threads; each wave handles 8 rows.
// Per row: 128 candidate keys (2/lane), packed key = (f32bits(d2) & ~0x7F) | j.
// Top-32 selection: sort four 32-blocks (asc/desc alternating), bitonic-split
// merge to two 32-sequences, clean (asc / desc), in-lane split, final clean.
__global__ __launch_bounds__(256, 8) void knn_edges_kernel(const float* __restrict__ pos,
                                                           float* __restrict__ out) {
    __shared__ float px[MM], py[MM], pz[MM], sqs[MM];
    const int blk = blockIdx.x;
    const int b = blk >> 2;            // blk / BPB
    const int sub = blk & (BPB - 1);
    const int tid = threadIdx.x;

    if (tid < MM) {
        const float* p = pos + (size_t)(b * MM + tid) * 3;
        float x = p[0], y = p[1], z = p[2];
        px[tid] = x; py[tid] = y; pz[tid] = z;
        sqs[tid] = __fadd_rn(__fadd_rn(__fmul_rn(x, x), __fmul_rn(y, y)), __fmul_rn(z, z));
    }
    __syncthreads();

    const int wave = tid >> 6;
    const int lane = tid & 63;

    // per-lane candidate coordinates, hoisted across the row loop
    const int j0 = lane, j1 = lane + 64;
    const float xa = px[j0], ya = py[j0], za = pz[j0], qa = sqs[j0];
    const float xb = px[j1], yb = py[j1], zb = pz[j1], qb = sqs[j1];

    const int row0 = sub * (MM / BPB) + wave * ROWS_PER_WAVE;

    for (int i = row0; i < row0 + ROWS_PER_WAVE; ++i) {
        const float xi = px[i], yi = py[i], zi = pz[i], qi = sqs[i];

        // ---- candidate keys ----
        float dot0 = __fadd_rn(__fadd_rn(__fmul_rn(xi, xa), __fmul_rn(yi, ya)), __fmul_rn(zi, za));
        float d20 = fmaxf(__fsub_rn(__fadd_rn(qi, qa), __fmul_rn(2.0f, dot0)), 0.0f);
        unsigned bits0 = (d20 < 25.0f) ? __float_as_uint(d20) : 0x7F800000u;
        unsigned k0 = (bits0 & 0xFFFFFF80u) | (unsigned)j0;

        float dot1 = __fadd_rn(__fadd_rn(__fmul_rn(xi, xb), __fmul_rn(yi, yb)), __fmul_rn(zi, zb));
        float d21 = fmaxf(__fsub_rn(__fadd_rn(qi, qb), __fmul_rn(2.0f, dot1)), 0.0f);
        unsigned bits1 = (d21 < 25.0f) ? __float_as_uint(d21) : 0x7F800000u;
        unsigned k1 = (bits1 & 0xFFFFFF80u) | (unsigned)j1;

        // ---- phase 1: sort the four 32-blocks (lower lanes asc, upper desc) ----
#define P1(S, ST) k0 = cexs<ST, p1mask(S, ST)>(k0); k1 = cexs<ST, p1mask(S, ST)>(k1);
        P1(2, 1)
        P1(4, 2)  P1(4, 1)
        P1(8, 4)  P1(8, 2)  P1(8, 1)
        P1(16, 8) P1(16, 4) P1(16, 2) P1(16, 1)
        P1(32, 16) P1(32, 8) P1(32, 4) P1(32, 2) P1(32, 1)
#undef P1

        // ---- phase 2: bitonic split across the 32-lane halves ----
        unsigned c  = k0, c2 = k1;
        {
            unsigned pc  = sx32(k0);
            unsigned pc2 = sx32(k1);
            c  = c  < pc  ? c  : pc;    // smallest 32 of candidates 0..63  (bitonic, dup halves)
            c2 = c2 < pc2 ? c2 : pc2;   // smallest 32 of candidates 64..127
        }

        // ---- phase 3: clean c ascending, c2 descending ----
#define P3(ST) c = cexs<ST, cleanmask(ST)>(c); c2 = cexs<ST, ~cleanmask(ST)>(c2);
        P3(16) P3(8) P3(4) P3(2) P3(1)
#undef P3

        // ---- phase 4: in-lane split of [c asc ; c2 desc] ----
        unsigned m = c < c2 ? c : c2;   // smallest 32 overall (bitonic)

        // ---- phase 5: final clean ascending ----
#define P5(ST) m = cexs<ST, cleanmask(ST)>(m);
        P5(16) P5(8) P5(4) P5(2) P5(1)
#undef P5

        // ---- epilogue: rank r = lane&31, duplicated across halves ----
        const int r = lane & 31;
        const unsigned key = m;
        const bool taken = (key & 0xFFFFFF80u) != 0x7F800000u;
        const int j = (int)(key & 127u);
        const int sel = taken ? j : i;

        float dxv = __fsub_rn(px[sel], xi);
        float dyv = __fsub_rn(py[sel], yi);
        float dzv = __fsub_rn(pz[sel], zi);
        float w = 0.0f;
        if (taken && sel != i) {
            w = sqrtf(__fadd_rn(__fadd_rn(__fmul_rn(dxv, dxv), __fmul_rn(dyv, dyv)),
                                __fmul_rn(dzv, dzv)));
        }

        const int node = b * MM + i;
        const int e = node * KK + r;
        float* vec = out + 3 * (size_t)NEDGE + (size_t)e * 3;
        if (lane < 32) {
            out[e] = (float)(b * MM + sel);            // src
            vec[0] = dxv;
            vec[1] = dyv;
        } else {
            out[NEDGE + e] = (float)node;              // dst
            out[2 * (size_t)NEDGE + e] = w;            // weight
            vec[2] = dzv;
        }
    }
}

extern "C" void kernel_launch(void* const* d_in, const int* in_sizes, int n_in,
                              void* d_out, int out_size, void* d_ws, size_t ws_size,
                              hipStream_t stream) {
    const float* pos = (const float*)d_in[0];
    float* out = (float*)d_out;
    hipLaunchKernelGGL(knn_edges_kernel, dim3(BB * BPB), dim3(256), 0, stream, pos, out);
}